// Round 2
// baseline (276.442 us; speedup 1.0000x reference)
//
#include <hip/hip_runtime.h>
#include <math.h>

#define BB 16
#define CC 512
#define NTOK 4096   // h*w
#define SS 8
#define TT 128      // token tile
#define RSTRIDE 36  // padded stride (floats) per token-group in reduce buffer; 36*4B=144B, 16B-aligned

// ---------------------------------------------------------------------------
// Kernel 1: logits[b][n][s] = sum_c x[b][c][n]*Wk[s][c]; also lsum[b][s] += sum_n exp(logit)
// grid = BB*32 = 512 blocks (2/CU), 256 threads.
// tn=tid&31 owns 4 consecutive tokens (float4); tc=tid>>5 owns 1/8 of c.
// No max-subtraction: logits ~ N(0,1), exp() is safe in fp32.
// ---------------------------------------------------------------------------
__global__ __launch_bounds__(256) void k_logits(const float* __restrict__ x,
                                                const float* __restrict__ Wk,
                                                float* __restrict__ logits,
                                                float* __restrict__ lsum) {
    __shared__ float wkT[CC * SS];            // [c][s], 16 KB
    __shared__ float red[8 * 32 * RSTRIDE];   // [tc][tn][i*8+s], 36 KB
    __shared__ float esum[4 * SS];
    const int tid   = threadIdx.x;
    const int tn    = tid & 31;
    const int tc    = tid >> 5;               // 0..7
    const int blk   = blockIdx.x;
    const int b     = blk >> 5;
    const int ntile = blk & 31;
    const int n0    = ntile * TT + tn * 4;

    for (int k = tid; k < CC * SS; k += 256) {
        int s = k >> 9;
        int c = k & (CC - 1);
        wkT[c * SS + s] = Wk[k];
    }
    __syncthreads();

    float acc[4][SS];
#pragma unroll
    for (int i = 0; i < 4; ++i)
#pragma unroll
        for (int s = 0; s < SS; ++s) acc[i][s] = 0.f;

    const float* xb = x + (size_t)b * CC * NTOK + n0;
#pragma unroll 8
    for (int k = 0; k < CC / 8; ++k) {        // 64 iters, 8 in flight
        int c = tc + k * 8;
        float4 x4 = *(const float4*)(xb + (size_t)c * NTOK);
        const float* wk = &wkT[c * SS];
#pragma unroll
        for (int s = 0; s < SS; ++s) {
            float w = wk[s];
            acc[0][s] += x4.x * w;
            acc[1][s] += x4.y * w;
            acc[2][s] += x4.z * w;
            acc[3][s] += x4.w * w;
        }
    }

    // partials: 16B-aligned region per thread -> ds_write_b128
    float4* myred = (float4*)&red[tc * (32 * RSTRIDE) + tn * RSTRIDE];
#pragma unroll
    for (int i = 0; i < 4; ++i) {
        myred[i * 2]     = make_float4(acc[i][0], acc[i][1], acc[i][2], acc[i][3]);
        myred[i * 2 + 1] = make_float4(acc[i][4], acc[i][5], acc[i][6], acc[i][7]);
    }
    __syncthreads();

    // reduce 1024 outputs (128 tok x 8 s) over 8 partials; fuse exp-sum.
    // s = flat&7 = tid&7 (constant per thread across j).
    float* outb = logits + ((size_t)b * NTOK + (size_t)ntile * TT) * SS;
    float es = 0.f;
#pragma unroll
    for (int j = 0; j < 4; ++j) {
        int flat = tid + j * 256;
        int tnp  = flat >> 5;
        int rem  = flat & 31;
        float v = 0.f;
#pragma unroll
        for (int t = 0; t < 8; ++t) v += red[t * (32 * RSTRIDE) + tnp * RSTRIDE + rem];
        outb[flat] = v;                       // coalesced
        es += __expf(v);
    }
    // reduce across lanes sharing lane&7 (same s)
    es += __shfl_down(es, 8, 64);
    es += __shfl_down(es, 16, 64);
    es += __shfl_down(es, 32, 64);
    const int lane = tid & 63, wave = tid >> 6;
    if (lane < SS) esum[wave * SS + lane] = es;
    __syncthreads();
    if (tid < SS) {
        float t = esum[tid] + esum[SS + tid] + esum[2 * SS + tid] + esum[3 * SS + tid];
        atomicAdd(&lsum[b * SS + tid], t);
    }
}

// ---------------------------------------------------------------------------
// Kernel 2: w[n,s] = exp(logit)/l, L1-renorm over s; out = relu(x + sum_s w*Wv[c,s])
// grid = BB*64 = 1024 blocks (4/CU), 256 threads. 128-token tiles, c halved.
// ---------------------------------------------------------------------------
__global__ __launch_bounds__(256) void k_out(const float* __restrict__ x,
                                             const float* __restrict__ Wv,
                                             const float* __restrict__ logits,
                                             const float* __restrict__ lsum,
                                             float* __restrict__ out) {
    __shared__ float wv[CC * SS];             // 16 KB
    const int tid   = threadIdx.x;
    const int tn    = tid & 31;
    const int tc    = tid >> 5;               // 0..7
    const int blk   = blockIdx.x;
    const int b     = blk >> 6;
    const int rest  = blk & 63;
    const int ntile = rest >> 1;
    const int chalf = rest & 1;
    const int n0    = ntile * TT + tn * 4;

    for (int k = tid; k < CC * SS; k += 256) wv[k] = Wv[k];

    float invl[SS];
    const float* lb = lsum + b * SS;
#pragma unroll
    for (int s = 0; s < SS; ++s) invl[s] = 1.0f / lb[s];

    // this thread's 4 tokens: 32 consecutive logit floats
    const float* lg = logits + ((size_t)b * NTOK + n0) * SS;
    float w[4][SS];
#pragma unroll
    for (int i = 0; i < 4; ++i) {
        float4 p0 = *(const float4*)(lg + i * 8);
        float4 p1 = *(const float4*)(lg + i * 8 + 4);
        float e[SS] = {p0.x, p0.y, p0.z, p0.w, p1.x, p1.y, p1.z, p1.w};
        float rs = 0.f;
#pragma unroll
        for (int s = 0; s < SS; ++s) {
            float p = __expf(e[s]) * invl[s];
            w[i][s] = p;
            rs += p;
        }
        float inv = 1.0f / (1e-9f + rs);
#pragma unroll
        for (int s = 0; s < SS; ++s) w[i][s] *= inv;
    }
    __syncthreads();

    const size_t xbase = (size_t)b * CC * NTOK + n0;
#pragma unroll 8
    for (int k = 0; k < CC / 16; ++k) {       // 32 iters, 8 in flight
        int c = chalf * (CC / 2) + tc + k * 8;
        const float* xp = x + xbase + (size_t)c * NTOK;
        float4 x4 = *(const float4*)xp;
        const float* wvc = &wv[c * SS];
        float o0 = 0.f, o1 = 0.f, o2 = 0.f, o3 = 0.f;
#pragma unroll
        for (int s = 0; s < SS; ++s) {
            float vv = wvc[s];
            o0 += w[0][s] * vv;
            o1 += w[1][s] * vv;
            o2 += w[2][s] * vv;
            o3 += w[3][s] * vv;
        }
        float4 y;
        y.x = fmaxf(x4.x + o0, 0.f);
        y.y = fmaxf(x4.y + o1, 0.f);
        y.z = fmaxf(x4.z + o2, 0.f);
        y.w = fmaxf(x4.w + o3, 0.f);
        *(float4*)(out + xbase + (size_t)c * NTOK) = y;
    }
}

// ---------------------------------------------------------------------------
extern "C" void kernel_launch(void* const* d_in, const int* in_sizes, int n_in,
                              void* d_out, int out_size, void* d_ws, size_t ws_size,
                              hipStream_t stream) {
    const float* x  = (const float*)d_in[0];   // [16][512][64][64]
    const float* Wk = (const float*)d_in[1];   // [8][512]
    const float* Wv = (const float*)d_in[2];   // [512][8]
    float* outp = (float*)d_out;

    float* logits = (float*)d_ws;                        // 16*4096*8 floats = 2 MB
    float* lsum   = logits + (size_t)BB * NTOK * SS;     // 128 floats

    hipMemsetAsync(lsum, 0, BB * SS * sizeof(float), stream);
    k_logits<<<BB * 32, 256, 0, stream>>>(x, Wk, logits, lsum);
    k_out<<<BB * 64, 256, 0, stream>>>(x, Wv, logits, lsum, outp);
}

// Round 3
// 271.521 us; speedup vs baseline: 1.0181x; 1.0181x over previous
//
#include <hip/hip_runtime.h>
#include <math.h>

#define BB 16
#define CC 512
#define NTOK 4096   // h*w
#define SS 8
#define TT 128      // token tile
#define NTILES (NTOK / TT)       // 32
#define RSTRIDE 36  // padded stride (floats) per token-group in reduce buffer

// ---------------------------------------------------------------------------
// Kernel 1: E[b][n][s] = exp(sum_c x[b][c][n]*Wk[s][c]);
//           esum_p[b][ntile][s] = sum_{n in tile} E  (no atomics, no memset)
// grid = BB*32 = 512 blocks (2/CU), 256 threads.
// tn=tid&31 owns 4 consecutive tokens (float4); tc=tid>>5 owns 1/8 of c.
// No max-subtraction: logits ~ N(0,1) (Wk scaled 1/sqrt(c)), exp() safe in fp32.
// ---------------------------------------------------------------------------
__global__ __launch_bounds__(256) void k_logits(const float* __restrict__ x,
                                                const float* __restrict__ Wk,
                                                float* __restrict__ E,
                                                float* __restrict__ esum_p) {
    __shared__ float wkT[CC * SS];            // [c][s], 16 KB
    __shared__ float red[8 * 32 * RSTRIDE];   // [tc][tn][i*8+s], 36 KB
    __shared__ float esum[4 * SS];
    const int tid   = threadIdx.x;
    const int tn    = tid & 31;
    const int tc    = tid >> 5;               // 0..7
    const int blk   = blockIdx.x;
    const int b     = blk >> 5;
    const int ntile = blk & 31;
    const int n0    = ntile * TT + tn * 4;

    for (int k = tid; k < CC * SS; k += 256) {
        int s = k >> 9;
        int c = k & (CC - 1);
        wkT[c * SS + s] = Wk[k];
    }
    __syncthreads();

    float acc[4][SS];
#pragma unroll
    for (int i = 0; i < 4; ++i)
#pragma unroll
        for (int s = 0; s < SS; ++s) acc[i][s] = 0.f;

    const float* xb = x + (size_t)b * CC * NTOK + n0;
#pragma unroll 8
    for (int k = 0; k < CC / 8; ++k) {        // 64 iters, 8 loads in flight
        int c = tc + k * 8;
        float4 x4 = *(const float4*)(xb + (size_t)c * NTOK);
        const float* wk = &wkT[c * SS];
#pragma unroll
        for (int s = 0; s < SS; ++s) {
            float w = wk[s];
            acc[0][s] += x4.x * w;
            acc[1][s] += x4.y * w;
            acc[2][s] += x4.z * w;
            acc[3][s] += x4.w * w;
        }
    }

    // partials: 16B-aligned region per thread -> ds_write_b128
    float4* myred = (float4*)&red[tc * (32 * RSTRIDE) + tn * RSTRIDE];
#pragma unroll
    for (int i = 0; i < 4; ++i) {
        myred[i * 2]     = make_float4(acc[i][0], acc[i][1], acc[i][2], acc[i][3]);
        myred[i * 2 + 1] = make_float4(acc[i][4], acc[i][5], acc[i][6], acc[i][7]);
    }
    __syncthreads();

    // reduce 1024 outputs (128 tok x 8 s) over 8 partials; store exp(); fuse exp-sum.
    // s = flat&7 = tid&7 (constant per thread across j).
    float* outb = E + ((size_t)b * NTOK + (size_t)ntile * TT) * SS;
    float es = 0.f;
#pragma unroll
    for (int j = 0; j < 4; ++j) {
        int flat = tid + j * 256;
        int tnp  = flat >> 5;
        int rem  = flat & 31;
        float v = 0.f;
#pragma unroll
        for (int t = 0; t < 8; ++t) v += red[t * (32 * RSTRIDE) + tnp * RSTRIDE + rem];
        float e = __expf(v);
        outb[flat] = e;                       // coalesced
        es += e;
    }
    // reduce across lanes sharing lane&7 (same s)
    es += __shfl_down(es, 8, 64);
    es += __shfl_down(es, 16, 64);
    es += __shfl_down(es, 32, 64);
    const int lane = tid & 63, wave = tid >> 6;
    if (lane < SS) esum[wave * SS + lane] = es;
    __syncthreads();
    if (tid < SS) {
        float t = esum[tid] + esum[SS + tid] + esum[2 * SS + tid] + esum[3 * SS + tid];
        esum_p[(b * NTILES + ntile) * SS + tid] = t;   // distinct slot per block
    }
}

// ---------------------------------------------------------------------------
// Kernel 2: w[n,s] = E/l, L1-renorm over s; out = relu(x + sum_s w*Wv[c,s])
// grid = BB*64 = 1024 blocks (4/CU), 256 threads. 128-token tiles, c halved.
// ---------------------------------------------------------------------------
__global__ __launch_bounds__(256) void k_out(const float* __restrict__ x,
                                             const float* __restrict__ Wv,
                                             const float* __restrict__ E,
                                             const float* __restrict__ esum_p,
                                             float* __restrict__ out) {
    __shared__ float wv[CC * SS];             // 16 KB
    __shared__ float ep[NTILES * SS];         // 256 partials for this b
    __shared__ float invl_s[SS];
    const int tid   = threadIdx.x;
    const int tn    = tid & 31;
    const int tc    = tid >> 5;               // 0..7
    const int blk   = blockIdx.x;
    const int b     = blk >> 6;
    const int rest  = blk & 63;
    const int ntile = rest >> 1;
    const int chalf = rest & 1;
    const int n0    = ntile * TT + tn * 4;

    ep[tid] = esum_p[b * (NTILES * SS) + tid];             // 256 coalesced
    for (int k = tid; k < CC * SS; k += 256) wv[k] = Wv[k];
    __syncthreads();
    if (tid < SS) {
        float t = 0.f;
#pragma unroll
        for (int j = 0; j < NTILES; ++j) t += ep[j * SS + tid];
        invl_s[tid] = 1.0f / t;
    }
    __syncthreads();

    float invl[SS];
#pragma unroll
    for (int s = 0; s < SS; ++s) invl[s] = invl_s[s];

    // this thread's 4 tokens: 32 consecutive E floats
    const float* lg = E + ((size_t)b * NTOK + n0) * SS;
    float w[4][SS];
#pragma unroll
    for (int i = 0; i < 4; ++i) {
        float4 p0 = *(const float4*)(lg + i * 8);
        float4 p1 = *(const float4*)(lg + i * 8 + 4);
        float e[SS] = {p0.x, p0.y, p0.z, p0.w, p1.x, p1.y, p1.z, p1.w};
        float rs = 0.f;
#pragma unroll
        for (int s = 0; s < SS; ++s) {
            float p = e[s] * invl[s];
            w[i][s] = p;
            rs += p;
        }
        float inv = 1.0f / (1e-9f + rs);
#pragma unroll
        for (int s = 0; s < SS; ++s) w[i][s] *= inv;
    }

    const size_t xbase = (size_t)b * CC * NTOK + n0;
#pragma unroll 8
    for (int k = 0; k < CC / 16; ++k) {       // 32 iters, 8 in flight
        int c = chalf * (CC / 2) + tc + k * 8;
        const float* xp = x + xbase + (size_t)c * NTOK;
        float4 x4 = *(const float4*)xp;
        const float* wvc = &wv[c * SS];
        float o0 = 0.f, o1 = 0.f, o2 = 0.f, o3 = 0.f;
#pragma unroll
        for (int s = 0; s < SS; ++s) {
            float vv = wvc[s];
            o0 += w[0][s] * vv;
            o1 += w[1][s] * vv;
            o2 += w[2][s] * vv;
            o3 += w[3][s] * vv;
        }
        float4 y;
        y.x = fmaxf(x4.x + o0, 0.f);
        y.y = fmaxf(x4.y + o1, 0.f);
        y.z = fmaxf(x4.z + o2, 0.f);
        y.w = fmaxf(x4.w + o3, 0.f);
        *(float4*)(out + xbase + (size_t)c * NTOK) = y;
    }
}

// ---------------------------------------------------------------------------
extern "C" void kernel_launch(void* const* d_in, const int* in_sizes, int n_in,
                              void* d_out, int out_size, void* d_ws, size_t ws_size,
                              hipStream_t stream) {
    const float* x  = (const float*)d_in[0];   // [16][512][64][64]
    const float* Wk = (const float*)d_in[1];   // [8][512]
    const float* Wv = (const float*)d_in[2];   // [512][8]
    float* outp = (float*)d_out;

    float* E      = (float*)d_ws;                         // 16*4096*8 floats = 2 MB
    float* esum_p = E + (size_t)BB * NTOK * SS;           // 16*32*8 = 4096 floats

    k_logits<<<BB * NTILES, 256, 0, stream>>>(x, Wk, E, esum_p);
    k_out<<<BB * NTILES * 2, 256, 0, stream>>>(x, Wv, E, esum_p, outp);
}

// Round 6
// 260.686 us; speedup vs baseline: 1.0604x; 1.0416x over previous
//
#include <hip/hip_runtime.h>
#include <math.h>

#define BB 16
#define CC 512
#define NTOK 4096   // h*w
#define SS 8
#define TT 128      // token tile
#define NTILES (NTOK / TT)       // 32
#define RSTRIDE 36  // padded stride (floats) per token-group in reduce buffer

// native 16B vector type acceptable to __builtin_nontemporal_store
typedef float nfloat4 __attribute__((ext_vector_type(4)));

// ---------------------------------------------------------------------------
// Kernel 1: E[b][n][s] = exp(sum_c x[b][c][n]*Wk[s][c]);
//           esum_p[b][ntile][s] = sum_{n in tile} E  (no atomics, no memset)
// grid = BB*32 = 512 blocks (2/CU), 256 threads.
// tn=tid&31 owns 4 consecutive tokens (float4); tc=tid>>5 owns 1/8 of c.
// No max-subtraction: logits ~ N(0,1) (Wk scaled 1/sqrt(c)), exp() safe in fp32.
// ---------------------------------------------------------------------------
__global__ __launch_bounds__(256) void k_logits(const float* __restrict__ x,
                                                const float* __restrict__ Wk,
                                                float* __restrict__ E,
                                                float* __restrict__ esum_p) {
    __shared__ float wkT[CC * SS];            // [c][s], 16 KB
    __shared__ float red[8 * 32 * RSTRIDE];   // [tc][tn][i*8+s], 36 KB
    __shared__ float esum[4 * SS];
    const int tid   = threadIdx.x;
    const int tn    = tid & 31;
    const int tc    = tid >> 5;               // 0..7
    const int blk   = blockIdx.x;
    const int b     = blk >> 5;
    const int ntile = blk & 31;
    const int n0    = ntile * TT + tn * 4;

    for (int k = tid; k < CC * SS; k += 256) {
        int s = k >> 9;
        int c = k & (CC - 1);
        wkT[c * SS + s] = Wk[k];
    }
    __syncthreads();

    float acc[4][SS];
#pragma unroll
    for (int i = 0; i < 4; ++i)
#pragma unroll
        for (int s = 0; s < SS; ++s) acc[i][s] = 0.f;

    const float* xb = x + (size_t)b * CC * NTOK + n0;
#pragma unroll 8
    for (int k = 0; k < CC / 8; ++k) {        // 64 iters, 8 loads in flight
        int c = tc + k * 8;
        float4 x4 = *(const float4*)(xb + (size_t)c * NTOK);
        const float* wk = &wkT[c * SS];
#pragma unroll
        for (int s = 0; s < SS; ++s) {
            float w = wk[s];
            acc[0][s] += x4.x * w;
            acc[1][s] += x4.y * w;
            acc[2][s] += x4.z * w;
            acc[3][s] += x4.w * w;
        }
    }

    // partials: 16B-aligned region per thread -> ds_write_b128
    float4* myred = (float4*)&red[tc * (32 * RSTRIDE) + tn * RSTRIDE];
#pragma unroll
    for (int i = 0; i < 4; ++i) {
        myred[i * 2]     = make_float4(acc[i][0], acc[i][1], acc[i][2], acc[i][3]);
        myred[i * 2 + 1] = make_float4(acc[i][4], acc[i][5], acc[i][6], acc[i][7]);
    }
    __syncthreads();

    // reduce 1024 outputs (128 tok x 8 s) over 8 partials; store exp(); fuse exp-sum.
    // s = flat&7 = tid&7 (constant per thread across j).
    float* outb = E + ((size_t)b * NTOK + (size_t)ntile * TT) * SS;
    float es = 0.f;
#pragma unroll
    for (int j = 0; j < 4; ++j) {
        int flat = tid + j * 256;
        int tnp  = flat >> 5;
        int rem  = flat & 31;
        float v = 0.f;
#pragma unroll
        for (int t = 0; t < 8; ++t) v += red[t * (32 * RSTRIDE) + tnp * RSTRIDE + rem];
        float e = __expf(v);
        outb[flat] = e;                       // coalesced
        es += e;
    }
    // reduce across lanes sharing lane&7 (same s)
    es += __shfl_down(es, 8, 64);
    es += __shfl_down(es, 16, 64);
    es += __shfl_down(es, 32, 64);
    const int lane = tid & 63, wave = tid >> 6;
    if (lane < SS) esum[wave * SS + lane] = es;
    __syncthreads();
    if (tid < SS) {
        float t = esum[tid] + esum[SS + tid] + esum[2 * SS + tid] + esum[3 * SS + tid];
        esum_p[(b * NTILES + ntile) * SS + tid] = t;   // distinct slot per block
    }
}

// ---------------------------------------------------------------------------
// Kernel 2: w[n,s] = E/l, L1-renorm over s; out = relu(x + sum_s w*Wv[c,s])
// grid = BB*64 = 1024 blocks (4/CU), 256 threads. 128-token tiles, c halved.
// Output stores are NON-TEMPORAL: out is write-only, keep x/E lines in cache.
// ---------------------------------------------------------------------------
__global__ __launch_bounds__(256) void k_out(const float* __restrict__ x,
                                             const float* __restrict__ Wv,
                                             const float* __restrict__ E,
                                             const float* __restrict__ esum_p,
                                             float* __restrict__ out) {
    __shared__ float wv[CC * SS];             // 16 KB
    __shared__ float ep[NTILES * SS];         // 256 partials for this b
    __shared__ float invl_s[SS];
    const int tid   = threadIdx.x;
    const int tn    = tid & 31;
    const int tc    = tid >> 5;               // 0..7
    const int blk   = blockIdx.x;
    const int b     = blk >> 6;
    const int rest  = blk & 63;
    const int ntile = rest >> 1;
    const int chalf = rest & 1;
    const int n0    = ntile * TT + tn * 4;

    ep[tid] = esum_p[b * (NTILES * SS) + tid];             // 256 coalesced
    for (int k = tid; k < CC * SS; k += 256) wv[k] = Wv[k];
    __syncthreads();
    if (tid < SS) {
        float t = 0.f;
#pragma unroll
        for (int j = 0; j < NTILES; ++j) t += ep[j * SS + tid];
        invl_s[tid] = 1.0f / t;
    }
    __syncthreads();

    float invl[SS];
#pragma unroll
    for (int s = 0; s < SS; ++s) invl[s] = invl_s[s];

    // this thread's 4 tokens: 32 consecutive E floats
    const float* lg = E + ((size_t)b * NTOK + n0) * SS;
    float w[4][SS];
#pragma unroll
    for (int i = 0; i < 4; ++i) {
        float4 p0 = *(const float4*)(lg + i * 8);
        float4 p1 = *(const float4*)(lg + i * 8 + 4);
        float e[SS] = {p0.x, p0.y, p0.z, p0.w, p1.x, p1.y, p1.z, p1.w};
        float rs = 0.f;
#pragma unroll
        for (int s = 0; s < SS; ++s) {
            float p = e[s] * invl[s];
            w[i][s] = p;
            rs += p;
        }
        float inv = 1.0f / (1e-9f + rs);
#pragma unroll
        for (int s = 0; s < SS; ++s) w[i][s] *= inv;
    }

    const size_t xbase = (size_t)b * CC * NTOK + n0;
#pragma unroll 8
    for (int k = 0; k < CC / 16; ++k) {       // 32 iters, 8 in flight
        int c = chalf * (CC / 2) + tc + k * 8;
        const float* xp = x + xbase + (size_t)c * NTOK;
        float4 x4 = *(const float4*)xp;
        const float* wvc = &wv[c * SS];
        float o0 = 0.f, o1 = 0.f, o2 = 0.f, o3 = 0.f;
#pragma unroll
        for (int s = 0; s < SS; ++s) {
            float vv = wvc[s];
            o0 += w[0][s] * vv;
            o1 += w[1][s] * vv;
            o2 += w[2][s] * vv;
            o3 += w[3][s] * vv;
        }
        nfloat4 y;
        y.x = fmaxf(x4.x + o0, 0.f);
        y.y = fmaxf(x4.y + o1, 0.f);
        y.z = fmaxf(x4.z + o2, 0.f);
        y.w = fmaxf(x4.w + o3, 0.f);
        __builtin_nontemporal_store(y, (nfloat4*)(out + xbase + (size_t)c * NTOK));
    }
}

// ---------------------------------------------------------------------------
extern "C" void kernel_launch(void* const* d_in, const int* in_sizes, int n_in,
                              void* d_out, int out_size, void* d_ws, size_t ws_size,
                              hipStream_t stream) {
    const float* x  = (const float*)d_in[0];   // [16][512][64][64]
    const float* Wk = (const float*)d_in[1];   // [8][512]
    const float* Wv = (const float*)d_in[2];   // [512][8]
    float* outp = (float*)d_out;

    float* E      = (float*)d_ws;                         // 16*4096*8 floats = 2 MB
    float* esum_p = E + (size_t)BB * NTOK * SS;           // 16*32*8 = 4096 floats

    k_logits<<<BB * NTILES, 256, 0, stream>>>(x, Wk, E, esum_p);
    k_out<<<BB * NTILES * 2, 256, 0, stream>>>(x, Wv, E, esum_p, outp);
}